// Round 10
// baseline (159.115 us; speedup 1.0000x reference)
//
#include <hip/hip_runtime.h>
#include <math.h>

#define Wd 256
#define Hd 256
#define KW 11
#define OUT_R 26              // output rows per block; stream 36 = 3 chunks of 12
#define RING 12               // ring size 12: slot=(2*jp+c)%12, chunk-independent
#define BLOCK 256

typedef float v2f __attribute__((ext_vector_type(2)));

__device__ __forceinline__ float rfl(float v) {
    return __int_as_float(__builtin_amdgcn_readfirstlane(__float_as_int(v)));
}

// Vertical-first SSIM, row-pair rounds inside the R6/R9-proven loop shape
// (outer runtime chunk loop `#pragma unroll 1`, inner fully-unrolled steps —
// the only structure measured to hold the register ring without scratch).
//
// R10: ring shrunk to 2 channels (x,y -> 24 VGPRs persistent); (x^2+y^2, xy)
// recomputed per emit step into STEP-LOCAL temps (die before horizontal
// phase), identical arithmetic to the 4-channel version. launch_bounds
// (256,6) -> 85-reg budget -> 24 waves/CU (vs R9's 16): attacks the measured
// latency-bound regime (VALU 38%, LDS ~45%, no pipe saturated).
__global__ __launch_bounds__(BLOCK, 6) void ssim_pair_kernel(
    const float* __restrict__ img1, const float* __restrict__ img2,
    const float* __restrict__ window, float* __restrict__ out, float scale)
{
    // rbE[buf][row][e+2] holds col 2e  (e=-2..130 -> idx 0..132)
    // rbO[buf][row][o+3] holds col 2o+1 (o=-3..129 -> idx 0..132)
    __shared__ __align__(16) float4 rbE[2][2][136];
    __shared__ __align__(16) float4 rbO[2][2][136];   // 17.4 KB
    __shared__ float red[BLOCK / 64];

    const float C1 = 1e-4f, C2 = 9e-4f;
    const int t = threadIdx.x;
    const int band = blockIdx.x;     // 0..9 (band 9 partial: 22 rows)
    const int plane = blockIdx.y;    // 0..143
    const float* __restrict__ p1 = img1 + (size_t)plane * (Hd * Wd);
    const float* __restrict__ p2 = img2 + (size_t)plane * (Hd * Wd);

    // Separable 1D weights (win2d = a outer a, sum a = 1); pin to SGPRs.
    float wl[KW];
    {
        float c = sqrtf(window[5 * KW + 5]);
        #pragma unroll
        for (int k = 0; k < KW; ++k)
            wl[k] = rfl(window[k * KW + 5] / c);
    }

    // Zero the column-halo cells once (never written by the row pass);
    // visible to readers via the first emit-step barrier.
    if (t < 4) {
        int buf = t >> 1, row = t & 1;
        float4 z = make_float4(0.f, 0.f, 0.f, 0.f);
        rbE[buf][row][0] = z; rbE[buf][row][1] = z;
        rbE[buf][row][130] = z; rbE[buf][row][131] = z; rbE[buf][row][132] = z;
        rbO[buf][row][0] = z; rbO[buf][row][1] = z; rbO[buf][row][2] = z;
        rbO[buf][row][131] = z; rbO[buf][row][132] = z;
    }

    const int ghbase = band * OUT_R - 5;   // global row of stream index 0

    v2f rXY[RING];                 // 24 persistent VGPRs
    float acc = 0.f;

    float px0, py0, px1, py1;   // current pair (stream rows i0, i0+1)
    {
        int g0 = ghbase, g1 = ghbase + 1;
        px0 = ((unsigned)g0 < (unsigned)Hd) ? p1[(g0 << 8) + t] : 0.f;
        py0 = ((unsigned)g0 < (unsigned)Hd) ? p2[(g0 << 8) + t] : 0.f;
        px1 = ((unsigned)g1 < (unsigned)Hd) ? p1[(g1 << 8) + t] : 0.f;
        py1 = ((unsigned)g1 < (unsigned)Hd) ? p2[(g1 << 8) + t] : 0.f;
    }

    #pragma unroll 1
    for (int ch = 0; ch < 3; ++ch) {
        #pragma unroll
        for (int jp = 0; jp < 6; ++jp) {
            const int i0 = 12 * ch + 2 * jp;        // uniform (ch runtime)
            const int s0 = (2 * jp) % RING;         // STATIC slot
            const int s1 = (2 * jp + 1) % RING;     // STATIC slot

            // ring insert rows i0, i0+1 (out-of-range rows carry zeros)
            {
                v2f v; v.x = px0; v.y = py0; rXY[s0] = v;
                v2f v2; v2.x = px1; v2.y = py1; rXY[s1] = v2;
            }
            // prefetch next pair (consumed next step)
            if (i0 + 2 < 36) {
                int g0 = ghbase + i0 + 2, g1 = ghbase + i0 + 3;
                px0 = ((unsigned)g0 < (unsigned)Hd) ? p1[(g0 << 8) + t] : 0.f;
                py0 = ((unsigned)g0 < (unsigned)Hd) ? p2[(g0 << 8) + t] : 0.f;
                px1 = ((unsigned)g1 < (unsigned)Hd) ? p1[(g1 << 8) + t] : 0.f;
                py1 = ((unsigned)g1 < (unsigned)Hd) ? p2[(g1 << 8) + t] : 0.f;
            }

            const int orow0 = band * OUT_R + i0 - 10;     // uniform
            if (i0 >= 10 && orow0 < Hd) {   // emit rows i0, i0+1
                const int buf = jp & 1;     // alternates across emit sequence

                // step-local (x^2+y^2, xy) per ring slot — dies after convs
                v2f sx[RING];
                #pragma unroll
                for (int u = 0; u < RING; ++u) {
                    v2f v = rXY[u];
                    v2f w2; w2.x = fmaf(v.x, v.x, v.y * v.y); w2.y = v.x * v.y;
                    sx[u] = w2;
                }

                // vertical 11-tap conv: row i0 slots (2jp+2+m)%12,
                //                       row i0+1 slots (2jp+3+m)%12 — STATIC
                v2f vAB0, vQP0, vAB1, vQP1;
                vAB0.x = vAB0.y = vQP0.x = vQP0.y = 0.f;
                vAB1.x = vAB1.y = vQP1.x = vQP1.y = 0.f;
                #pragma unroll
                for (int m = 0; m < KW; ++m) {
                    const int sa = (2 * jp + 2 + m) % RING;
                    const int sb = (2 * jp + 3 + m) % RING;
                    float w = wl[m];
                    vAB0 += w * rXY[sa];  vQP0 += w * sx[sa];
                    vAB1 += w * rXY[sb];  vQP1 += w * sx[sb];
                }
                const int half = t >> 1;
                if (t & 1) {
                    rbO[buf][0][half + 3] = make_float4(vAB0.x, vAB0.y, vQP0.x, vQP0.y);
                    rbO[buf][1][half + 3] = make_float4(vAB1.x, vAB1.y, vQP1.x, vQP1.y);
                } else {
                    rbE[buf][0][half + 2] = make_float4(vAB0.x, vAB0.y, vQP0.x, vQP0.y);
                    rbE[buf][1][half + 2] = make_float4(vAB1.x, vAB1.y, vQP1.x, vQP1.y);
                }
                __syncthreads();

                // horizontal: all 256 lanes. waves 0-1 -> row 0, 2-3 -> row 1
                const int r = t >> 7, cp = t & 127;   // output cols 2cp, 2cp+1
                const float4* bE = &rbE[buf][r][cp];
                const float4* bO = &rbO[buf][r][cp];
                v2f a0, q0, a1, q1;
                a0.x = a0.y = q0.x = q0.y = 0.f;
                a1.x = a1.y = q1.x = q1.y = 0.f;
                #pragma unroll
                for (int k = 0; k < 6; ++k) {
                    float4 vO = bO[k];                 // ds_read_b128
                    v2f oab; oab.x = vO.x; oab.y = vO.y;
                    v2f oqp; oqp.x = vO.z; oqp.y = vO.w;
                    a0 += wl[2 * k] * oab;  q0 += wl[2 * k] * oqp;
                    if (k >= 1) { a1 += wl[2 * k - 1] * oab;  q1 += wl[2 * k - 1] * oqp; }
                    float4 vE = bE[k];                 // ds_read_b128
                    v2f eab; eab.x = vE.x; eab.y = vE.y;
                    v2f eqp; eqp.x = vE.z; eqp.y = vE.w;
                    a1 += wl[2 * k] * eab;  q1 += wl[2 * k] * eqp;
                    if (k <= 4) { a0 += wl[2 * k + 1] * eab;  q0 += wl[2 * k + 1] * eqp; }
                }
                {
                    float mu1 = a0.x, mu2 = a0.y, sq = q0.x, sp = q0.y;
                    float mu1sq = mu1 * mu1, mu2sq = mu2 * mu2, mu12 = mu1 * mu2;
                    float musum = mu1sq + mu2sq;
                    float num = (2.f * mu12 + C1) * (2.f * (sp - mu12) + C2);
                    float den = (musum + C1) * ((sq - musum) + C2);
                    acc += num * __builtin_amdgcn_rcpf(den);
                }
                {
                    float mu1 = a1.x, mu2 = a1.y, sq = q1.x, sp = q1.y;
                    float mu1sq = mu1 * mu1, mu2sq = mu2 * mu2, mu12 = mu1 * mu2;
                    float musum = mu1sq + mu2sq;
                    float num = (2.f * mu12 + C1) * (2.f * (sp - mu12) + C2);
                    float den = (musum + C1) * ((sq - musum) + C2);
                    acc += num * __builtin_amdgcn_rcpf(den);
                }
            }
        }
    }

    // --- block reduction + fused global reduce (atomic) ---
    #pragma unroll
    for (int off = 32; off > 0; off >>= 1)
        acc += __shfl_down(acc, off, 64);
    int wave = t >> 6;
    if ((t & 63) == 0) red[wave] = acc;
    __syncthreads();
    if (t == 0) {
        float partial = red[0] + red[1] + red[2] + red[3];
        float v = partial * scale;                 // scale = -1/count
        if (band == 0 && plane == 0) v += 1.0f;    // out = 1 - sum/count
        atomicAdd(out, v);
    }
}

extern "C" void kernel_launch(void* const* d_in, const int* in_sizes, int n_in,
                              void* d_out, int out_size, void* d_ws, size_t ws_size,
                              hipStream_t stream) {
    const float* img1   = (const float*)d_in[0];
    const float* img2   = (const float*)d_in[1];
    const float* window = (const float*)d_in[2];
    float* out = (float*)d_out;

    const int planes = 16 * 9;                     // 144
    const int bands = (Hd + OUT_R - 1) / OUT_R;    // 10 (last band 22 rows)

    hipMemsetAsync(out, 0, sizeof(float), stream);

    const float scale = -(float)(1.0 / ((double)planes * Hd * Wd));
    dim3 grid(bands, planes);
    ssim_pair_kernel<<<grid, BLOCK, 0, stream>>>(img1, img2, window, out, scale);
}

// Round 11
// 134.685 us; speedup vs baseline: 1.1814x; 1.1814x over previous
//
#include <hip/hip_runtime.h>
#include <math.h>

#define Wd 256
#define Hd 256
#define KW 11
#define OUT_R 14              // output rows per block; stream 24 = 2 chunks of 12
#define RING 12               // ring size 12: slot=(2*jp+c)%12, chunk-independent
#define NCH 2                 // chunks per block
#define BLOCK 256

typedef float v2f __attribute__((ext_vector_type(2)));

__device__ __forceinline__ float rfl(float v) {
    return __int_as_float(__builtin_amdgcn_readfirstlane(__float_as_int(v)));
}

// Vertical-first SSIM, row-pair rounds inside the R6/R9-proven loop shape
// (outer runtime chunk loop `#pragma unroll 1`, inner fully-unrolled steps —
// the only structure measured to hold the 4-channel register ring without
// scratch; R7/R8 straight-line and R10 tight-reg variants all spilled).
//
// R11 = R9 body with OUT_R 26->14: grid 1440->2736 blocks (10.7/CU) attacks
// the measured latency-bound regime (R9: LDS ~45% busy, VALU 38%, HBM 14%,
// nothing saturated) with more co-resident blocks instead of fewer registers
// (R10's spill failure). Resource caps allow ~8 blocks/CU (VGPR 48, 17.9 KB).
__global__ __launch_bounds__(BLOCK, 4) void ssim_pair_kernel(
    const float* __restrict__ img1, const float* __restrict__ img2,
    const float* __restrict__ window, float* __restrict__ out, float scale)
{
    // rbE[buf][row][e+2] holds col 2e  (e=-2..130 -> idx 0..132)
    // rbO[buf][row][o+3] holds col 2o+1 (o=-3..129 -> idx 0..132)
    __shared__ __align__(16) float4 rbE[2][2][136];
    __shared__ __align__(16) float4 rbO[2][2][136];   // 17.4 KB
    __shared__ float red[BLOCK / 64];

    const float C1 = 1e-4f, C2 = 9e-4f;
    const int t = threadIdx.x;
    const int band = blockIdx.x;     // 0..18 (band 18 partial: 4 rows)
    const int plane = blockIdx.y;    // 0..143
    const float* __restrict__ p1 = img1 + (size_t)plane * (Hd * Wd);
    const float* __restrict__ p2 = img2 + (size_t)plane * (Hd * Wd);

    // Separable 1D weights (win2d = a outer a, sum a = 1); pin to SGPRs.
    float wl[KW];
    {
        float c = sqrtf(window[5 * KW + 5]);
        #pragma unroll
        for (int k = 0; k < KW; ++k)
            wl[k] = rfl(window[k * KW + 5] / c);
    }

    // Zero the column-halo cells once (never written by the row pass);
    // visible to readers via the first emit-step barrier.
    if (t < 4) {
        int buf = t >> 1, row = t & 1;
        float4 z = make_float4(0.f, 0.f, 0.f, 0.f);
        rbE[buf][row][0] = z; rbE[buf][row][1] = z;
        rbE[buf][row][130] = z; rbE[buf][row][131] = z; rbE[buf][row][132] = z;
        rbO[buf][row][0] = z; rbO[buf][row][1] = z; rbO[buf][row][2] = z;
        rbO[buf][row][131] = z; rbO[buf][row][132] = z;
    }

    const int ghbase = band * OUT_R - 5;   // global row of stream index 0

    v2f rXY[RING], rQP[RING];
    float acc = 0.f;

    float px0, py0, px1, py1;   // current pair (stream rows i0, i0+1)
    {
        int g0 = ghbase, g1 = ghbase + 1;
        px0 = ((unsigned)g0 < (unsigned)Hd) ? p1[(g0 << 8) + t] : 0.f;
        py0 = ((unsigned)g0 < (unsigned)Hd) ? p2[(g0 << 8) + t] : 0.f;
        px1 = ((unsigned)g1 < (unsigned)Hd) ? p1[(g1 << 8) + t] : 0.f;
        py1 = ((unsigned)g1 < (unsigned)Hd) ? p2[(g1 << 8) + t] : 0.f;
    }

    #pragma unroll 1
    for (int ch = 0; ch < NCH; ++ch) {
        #pragma unroll
        for (int jp = 0; jp < 6; ++jp) {
            const int i0 = 12 * ch + 2 * jp;        // uniform (ch runtime)
            const int s0 = (2 * jp) % RING;         // STATIC slot
            const int s1 = (2 * jp + 1) % RING;     // STATIC slot

            // ring insert rows i0, i0+1 (out-of-range rows carry zeros)
            {
                v2f v; v.x = px0; v.y = py0; rXY[s0] = v;
                v2f q; q.x = fmaf(px0, px0, py0 * py0); q.y = px0 * py0; rQP[s0] = q;
                v2f v2; v2.x = px1; v2.y = py1; rXY[s1] = v2;
                v2f q2; q2.x = fmaf(px1, px1, py1 * py1); q2.y = px1 * py1; rQP[s1] = q2;
            }
            // prefetch next pair (consumed next step)
            if (i0 + 2 < 12 * NCH) {
                int g0 = ghbase + i0 + 2, g1 = ghbase + i0 + 3;
                px0 = ((unsigned)g0 < (unsigned)Hd) ? p1[(g0 << 8) + t] : 0.f;
                py0 = ((unsigned)g0 < (unsigned)Hd) ? p2[(g0 << 8) + t] : 0.f;
                px1 = ((unsigned)g1 < (unsigned)Hd) ? p1[(g1 << 8) + t] : 0.f;
                py1 = ((unsigned)g1 < (unsigned)Hd) ? p2[(g1 << 8) + t] : 0.f;
            }

            const int orow0 = band * OUT_R + i0 - 10;     // uniform, even
            if (i0 >= 10 && orow0 < Hd) {   // emit rows i0, i0+1
                const int buf = jp & 1;     // alternates across emit sequence
                // vertical 11-tap conv: row i0 slots (2jp+2+m)%12,
                //                       row i0+1 slots (2jp+3+m)%12 — STATIC
                v2f vAB0, vQP0, vAB1, vQP1;
                vAB0.x = vAB0.y = vQP0.x = vQP0.y = 0.f;
                vAB1.x = vAB1.y = vQP1.x = vQP1.y = 0.f;
                #pragma unroll
                for (int m = 0; m < KW; ++m) {
                    const int sa = (2 * jp + 2 + m) % RING;
                    const int sb = (2 * jp + 3 + m) % RING;
                    float w = wl[m];
                    vAB0 += w * rXY[sa];  vQP0 += w * rQP[sa];
                    vAB1 += w * rXY[sb];  vQP1 += w * rQP[sb];
                }
                const int half = t >> 1;
                if (t & 1) {
                    rbO[buf][0][half + 3] = make_float4(vAB0.x, vAB0.y, vQP0.x, vQP0.y);
                    rbO[buf][1][half + 3] = make_float4(vAB1.x, vAB1.y, vQP1.x, vQP1.y);
                } else {
                    rbE[buf][0][half + 2] = make_float4(vAB0.x, vAB0.y, vQP0.x, vQP0.y);
                    rbE[buf][1][half + 2] = make_float4(vAB1.x, vAB1.y, vQP1.x, vQP1.y);
                }
                __syncthreads();

                // horizontal: all 256 lanes. waves 0-1 -> row 0, 2-3 -> row 1
                const int r = t >> 7, cp = t & 127;   // output cols 2cp, 2cp+1
                const float4* bE = &rbE[buf][r][cp];
                const float4* bO = &rbO[buf][r][cp];
                v2f a0, q0, a1, q1;
                a0.x = a0.y = q0.x = q0.y = 0.f;
                a1.x = a1.y = q1.x = q1.y = 0.f;
                #pragma unroll
                for (int k = 0; k < 6; ++k) {
                    float4 vO = bO[k];                 // ds_read_b128
                    v2f oab; oab.x = vO.x; oab.y = vO.y;
                    v2f oqp; oqp.x = vO.z; oqp.y = vO.w;
                    a0 += wl[2 * k] * oab;  q0 += wl[2 * k] * oqp;
                    if (k >= 1) { a1 += wl[2 * k - 1] * oab;  q1 += wl[2 * k - 1] * oqp; }
                    float4 vE = bE[k];                 // ds_read_b128
                    v2f eab; eab.x = vE.x; eab.y = vE.y;
                    v2f eqp; eqp.x = vE.z; eqp.y = vE.w;
                    a1 += wl[2 * k] * eab;  q1 += wl[2 * k] * eqp;
                    if (k <= 4) { a0 += wl[2 * k + 1] * eab;  q0 += wl[2 * k + 1] * eqp; }
                }
                {
                    float mu1 = a0.x, mu2 = a0.y, sq = q0.x, sp = q0.y;
                    float mu1sq = mu1 * mu1, mu2sq = mu2 * mu2, mu12 = mu1 * mu2;
                    float musum = mu1sq + mu2sq;
                    float num = (2.f * mu12 + C1) * (2.f * (sp - mu12) + C2);
                    float den = (musum + C1) * ((sq - musum) + C2);
                    acc += num * __builtin_amdgcn_rcpf(den);
                }
                {
                    float mu1 = a1.x, mu2 = a1.y, sq = q1.x, sp = q1.y;
                    float mu1sq = mu1 * mu1, mu2sq = mu2 * mu2, mu12 = mu1 * mu2;
                    float musum = mu1sq + mu2sq;
                    float num = (2.f * mu12 + C1) * (2.f * (sp - mu12) + C2);
                    float den = (musum + C1) * ((sq - musum) + C2);
                    acc += num * __builtin_amdgcn_rcpf(den);
                }
            }
        }
    }

    // --- block reduction + fused global reduce (atomic) ---
    #pragma unroll
    for (int off = 32; off > 0; off >>= 1)
        acc += __shfl_down(acc, off, 64);
    int wave = t >> 6;
    if ((t & 63) == 0) red[wave] = acc;
    __syncthreads();
    if (t == 0) {
        float partial = red[0] + red[1] + red[2] + red[3];
        float v = partial * scale;                 // scale = -1/count
        if (band == 0 && plane == 0) v += 1.0f;    // out = 1 - sum/count
        atomicAdd(out, v);
    }
}

extern "C" void kernel_launch(void* const* d_in, const int* in_sizes, int n_in,
                              void* d_out, int out_size, void* d_ws, size_t ws_size,
                              hipStream_t stream) {
    const float* img1   = (const float*)d_in[0];
    const float* img2   = (const float*)d_in[1];
    const float* window = (const float*)d_in[2];
    float* out = (float*)d_out;

    const int planes = 16 * 9;                     // 144
    const int bands = (Hd + OUT_R - 1) / OUT_R;    // 19 (last band 4 rows)

    hipMemsetAsync(out, 0, sizeof(float), stream);

    const float scale = -(float)(1.0 / ((double)planes * Hd * Wd));
    dim3 grid(bands, planes);
    ssim_pair_kernel<<<grid, BLOCK, 0, stream>>>(img1, img2, window, out, scale);
}